// Round 7
// baseline (86.868 us; speedup 1.0000x reference)
//
#include <hip/hip_runtime.h>
#include <math.h>

// Problem constants
#define B_   2
#define C_   32
#define H_   176
#define W_   608
#define HO_  351
#define WO_  1215
#define PLANE_O (HO_ * WO_)          // 426465
#define OUT1_O  (B_ * C_ * PLANE_O)  // 27293760 (mult of 4 -> same alignment)
#define EPS_ 1e-20f
#define NTH  256
#define W4   (W_ / 4)                // 152 float4 per input row
#define HW_  304                     // half-row length (col-parity split)
#define NROWS 3                      // fused rows per block

typedef float f4_t __attribute__((ext_vector_type(4)));
typedef float f2_t __attribute__((ext_vector_type(2)));

__device__ __forceinline__ float softplus_f(float x) {
    return fmaxf(x, 0.0f) + log1pf(expf(-fabsf(x)));
}

// Block = (row-group g, plane). 4 waves; wave w owns output row oy = 4g+w.
// Fused input rows 2g..2g+2 staged in LDS, split by column parity so the
// consume phase reads are stride-1 (conflict-free).
extern "C" __global__ __launch_bounds__(NTH, 8)
void structn_rows(const float* __restrict__ d,
                  const float* __restrict__ cd,
                  const float* __restrict__ gy,
                  const float* __restrict__ cgy,
                  const float* __restrict__ wpr,
                  const float* __restrict__ swr,
                  const float* __restrict__ bias,
                  float* __restrict__ out)
{
    __shared__ float s_nE[NROWS * HW_];   // cgy_f*gy_f, even input cols
    __shared__ float s_nO[NROWS * HW_];   // odd cols
    __shared__ float s_cE[NROWS * HW_];   // cgy_f, even cols
    __shared__ float s_cO[NROWS * HW_];   // odd cols

    const int g     = blockIdx.x;     // 88 row groups
    const int plane = blockIdx.y;     // 64 planes
    const int c     = plane & (C_ - 1);

    // ---- per-channel constants (wave-uniform, in-block) ----
    float sw[9];
#pragma unroll
    for (int k = 0; k < 9; ++k) sw[k] = softplus_f(swr[c * 9 + k]);
    const float wp      = softplus_f(wpr[c]);
    const float inv_wp1 = 1.0f / (wp + 1.0f);
    const float bv      = bias[c];
    const float icd_ee  = 1.0f / (sw[4] + EPS_);
    const float icd_eo  = 1.0f / (sw[3] + sw[5] + EPS_);
    const float icd_oe  = 1.0f / (sw[1] + sw[7] + EPS_);
    const float icd_oo  = 1.0f / (sw[0] + sw[2] + sw[6] + sw[8] + EPS_);

    const int r0  = g * 2;                                  // first fused row
    const int nrf = (r0 + NROWS - 1 <= H_ - 1) ? NROWS : (H_ - r0);

    const int pbase = plane * (H_ * W_);
    const float* __restrict__ dP  = d   + pbase;
    const float* __restrict__ cdP = cd  + pbase;
    const float* __restrict__ gyP = gy  + pbase;
    const float* __restrict__ cgP = cgy + pbase;

    // ---- stage: 2-task unroll, all loads issued before compute ----
    const int ntask = nrf * W4;            // 456 (or 304 last group)
    const int idx0  = threadIdx.x;         // always < ntask (ntask >= 304)
    const int idx1  = threadIdx.x + NTH;
    const bool has1 = (idx1 < ntask);

    // task A addresses
    const int rfA = idx0 / W4;
    const int iwA = (idx0 - rfA * W4) << 2;
    const int iyA = r0 + rfA;
    const int upA = (iyA == 0)      ? (H_ - 1) : iyA - 1;
    const int dnA = (iyA == H_ - 1) ? 0        : iyA + 1;
    const float muA = (iyA > 0)      ? 1.0f : 0.0f;
    const float mdA = (iyA < H_ - 1) ? 1.0f : 0.0f;

    const f4_t duA = *(const f4_t*)(dP  + upA * W_ + iwA);
    const f4_t ddA = *(const f4_t*)(dP  + dnA * W_ + iwA);
    const f4_t cuA = *(const f4_t*)(cdP + upA * W_ + iwA);
    const f4_t cnA = *(const f4_t*)(cdP + dnA * W_ + iwA);
    const f4_t ggA = *(const f4_t*)(gyP + iyA * W_ + iwA);
    const f4_t cgA = *(const f4_t*)(cgP + iyA * W_ + iwA);

    // task B addresses + loads (predicated)
    f4_t duB, ddB, cuB, cnB, ggB, cgB;
    int rfB = 0, iwB = 0;
    float muB = 0.f, mdB = 0.f;
    if (has1) {
        rfB = idx1 / W4;
        iwB = (idx1 - rfB * W4) << 2;
        const int iyB = r0 + rfB;
        const int upB = (iyB == 0)      ? (H_ - 1) : iyB - 1;
        const int dnB = (iyB == H_ - 1) ? 0        : iyB + 1;
        muB = (iyB > 0)      ? 1.0f : 0.0f;
        mdB = (iyB < H_ - 1) ? 1.0f : 0.0f;
        duB = *(const f4_t*)(dP  + upB * W_ + iwB);
        ddB = *(const f4_t*)(dP  + dnB * W_ + iwB);
        cuB = *(const f4_t*)(cdP + upB * W_ + iwB);
        cnB = *(const f4_t*)(cdP + dnB * W_ + iwB);
        ggB = *(const f4_t*)(gyP + iyB * W_ + iwB);
        cgB = *(const f4_t*)(cgP + iyB * W_ + iwB);
    }

#define FUSE_STORE(du, dd, cu, cn, gg, cg, mu, md, rf, iw)                      \
    {                                                                           \
        f4_t sn4, sc4;                                                          \
        _Pragma("unroll")                                                       \
        for (int e = 0; e < 4; ++e) {                                           \
            const float cuv = (cu)[e] * (mu);                                   \
            const float cnv = (cn)[e] * (md);                                   \
            const float cfd = cuv * cuv;                                        \
            const float rs  = __builtin_amdgcn_rcpf(fmaf(cuv, (du)[e], cnv * (dd)[e])); \
            const float gfd = 0.5f * ((dd)[e] - (du)[e]) * (cuv + cnv) * rs;    \
            const float num = fmaf(wp * (cg)[e], (gg)[e], cfd * gfd);           \
            const float den = fmaf(wp, (cg)[e], cfd);                           \
            sn4[e] = num * inv_wp1;                                             \
            sc4[e] = den * inv_wp1;                                             \
        }                                                                       \
        const int eo = (rf) * HW_ + ((iw) >> 1);                                \
        f2_t v;                                                                 \
        v[0] = sn4[0]; v[1] = sn4[2];  *(f2_t*)(s_nE + eo) = v;                 \
        v[0] = sn4[1]; v[1] = sn4[3];  *(f2_t*)(s_nO + eo) = v;                 \
        v[0] = sc4[0]; v[1] = sc4[2];  *(f2_t*)(s_cE + eo) = v;                 \
        v[0] = sc4[1]; v[1] = sc4[3];  *(f2_t*)(s_cO + eo) = v;                 \
    }

    FUSE_STORE(duA, ddA, cuA, cnA, ggA, cgA, muA, mdA, rfA, iwA)
    if (has1) FUSE_STORE(duB, ddB, cuB, cnB, ggB, cgB, muB, mdB, rfB, iwB)
#undef FUSE_STORE

    __syncthreads();

    // ---- consume: wave w -> output row oy = 4g+w ----
    const int w    = threadIdx.x >> 6;
    const int lane = threadIdx.x & 63;
    const int oy   = g * 4 + w;
    if (oy >= HO_) return;

    const int p   = w & 1;       // output-row parity (wave-uniform)
    const int lrA = w >> 1;      // local fused row index

    const int ro0 = plane * PLANE_O + oy * WO_;
    float* __restrict__ o0 = out + ro0;
    float* __restrict__ o1 = out + OUT1_O + ro0;

    const int h  = (4 - (ro0 & 3)) & 3;   // head scalars to 16B alignment
    const int n4 = (WO_ - h) >> 2;        // aligned float4 chunks
    const int q  = h & 1;                 // chunk col parity
    const int r  = (h >> 1) & 1;          // j0 parity

    const float icdC = p ? icd_oe : icd_ee;
    const float icdO = p ? icd_oo : icd_eo;
    const float i0 = q ? icdO : icdC;
    const float i1 = q ? icdC : icdO;

    const float* __restrict__ nAE = s_nE + lrA * HW_;
    const float* __restrict__ nAO = s_nO + lrA * HW_;
    const float* __restrict__ cAE = s_cE + lrA * HW_;
    const float* __restrict__ cAO = s_cO + lrA * HW_;

#define VAL(E, O, j) (((j) & 1) ? (O)[((j) - 1) >> 1] : (E)[(j) >> 1])

    if (p == 0) {
        if (lane < 3) {
            const int ox = (lane < h) ? lane : (h + (n4 << 2) + lane - h);
            float den, nom, icd;
            if ((ox & 1) == 0) {
                const int j = ox >> 1;
                den = VAL(cAE, cAO, j) * sw[4];
                nom = VAL(nAE, nAO, j) * sw[4];
                icd = icd_ee;
            } else {
                const int j = (ox - 1) >> 1;
                den = VAL(cAE, cAO, j) * sw[5] + VAL(cAE, cAO, j + 1) * sw[3];
                nom = VAL(nAE, nAO, j) * sw[5] + VAL(nAE, nAO, j + 1) * sw[3];
                icd = icd_eo;
            }
            o0[ox] = fmaf(0.5f * nom, __builtin_amdgcn_rcpf(den + EPS_), bv);
            o1[ox] = den * icd;
        }
        const float* pa0 = r ? nAO : nAE;
        const float* pa1 = r ? nAE + 1 : nAO;
        const float* px0 = r ? cAO : cAE;
        const float* px1 = r ? cAE + 1 : cAO;

        for (int k = lane; k < n4; k += 64) {
            const float a0 = pa0[k], a1 = pa1[k], a2 = pa0[k + 1];
            const float x0 = px0[k], x1 = px1[k], x2 = px0[k + 1];
            const float dC0 = x0 * sw[4], dC1 = x1 * sw[4], dC2 = x2 * sw[4];
            const float nC0 = a0 * sw[4], nC1 = a1 * sw[4], nC2 = a2 * sw[4];
            const float dF0 = x0 * sw[5] + x1 * sw[3];
            const float dF1 = x1 * sw[5] + x2 * sw[3];
            const float nF0 = a0 * sw[5] + a1 * sw[3];
            const float nF1 = a1 * sw[5] + a2 * sw[3];

            const float d0 = q ? dF0 : dC0, n0 = q ? nF0 : nC0;
            const float d1 = q ? dC1 : dF0, n1 = q ? nC1 : nF0;
            const float d2 = q ? dF1 : dC1, n2 = q ? nF1 : nC1;
            const float d3 = q ? dC2 : dF1, n3 = q ? nC2 : nF1;

            f4_t gv, qv;
            gv[0] = fmaf(0.5f * n0, __builtin_amdgcn_rcpf(d0 + EPS_), bv);
            gv[1] = fmaf(0.5f * n1, __builtin_amdgcn_rcpf(d1 + EPS_), bv);
            gv[2] = fmaf(0.5f * n2, __builtin_amdgcn_rcpf(d2 + EPS_), bv);
            gv[3] = fmaf(0.5f * n3, __builtin_amdgcn_rcpf(d3 + EPS_), bv);
            qv[0] = d0 * i0; qv[1] = d1 * i1; qv[2] = d2 * i0; qv[3] = d3 * i1;

            const int c0 = h + (k << 2);
            __builtin_nontemporal_store(gv, (f4_t*)(o0 + c0));
            __builtin_nontemporal_store(qv, (f4_t*)(o1 + c0));
        }
    } else {
        const float* __restrict__ nBE = nAE + HW_;
        const float* __restrict__ nBO = nAO + HW_;
        const float* __restrict__ cBE = cAE + HW_;
        const float* __restrict__ cBO = cAO + HW_;

        if (lane < 3) {
            const int ox = (lane < h) ? lane : (h + (n4 << 2) + lane - h);
            float den, nom, icd;
            if ((ox & 1) == 0) {
                const int j = ox >> 1;
                den = VAL(cAE, cAO, j) * sw[7] + VAL(cBE, cBO, j) * sw[1];
                nom = VAL(nAE, nAO, j) * sw[7] + VAL(nBE, nBO, j) * sw[1];
                icd = icd_oe;
            } else {
                const int j = (ox - 1) >> 1;
                den = VAL(cAE, cAO, j) * sw[8] + VAL(cAE, cAO, j + 1) * sw[6]
                    + VAL(cBE, cBO, j) * sw[2] + VAL(cBE, cBO, j + 1) * sw[0];
                nom = VAL(nAE, nAO, j) * sw[8] + VAL(nAE, nAO, j + 1) * sw[6]
                    + VAL(nBE, nBO, j) * sw[2] + VAL(nBE, nBO, j + 1) * sw[0];
                icd = icd_oo;
            }
            o0[ox] = fmaf(0.5f * nom, __builtin_amdgcn_rcpf(den + EPS_), bv);
            o1[ox] = den * icd;
        }

        const float* pa0 = r ? nAO : nAE;
        const float* pa1 = r ? nAE + 1 : nAO;
        const float* px0 = r ? cAO : cAE;
        const float* px1 = r ? cAE + 1 : cAO;
        const float* pb0 = r ? nBO : nBE;
        const float* pb1 = r ? nBE + 1 : nBO;
        const float* py0 = r ? cBO : cBE;
        const float* py1 = r ? cBE + 1 : cBO;

        for (int k = lane; k < n4; k += 64) {
            const float a0 = pa0[k], a1 = pa1[k], a2 = pa0[k + 1];
            const float x0 = px0[k], x1 = px1[k], x2 = px0[k + 1];
            const float b0 = pb0[k], b1 = pb1[k], b2 = pb0[k + 1];
            const float y0 = py0[k], y1 = py1[k], y2 = py0[k + 1];

            const float dC0 = x0 * sw[7] + y0 * sw[1];
            const float dC1 = x1 * sw[7] + y1 * sw[1];
            const float dC2 = x2 * sw[7] + y2 * sw[1];
            const float nC0 = a0 * sw[7] + b0 * sw[1];
            const float nC1 = a1 * sw[7] + b1 * sw[1];
            const float nC2 = a2 * sw[7] + b2 * sw[1];
            const float dF0 = x0 * sw[8] + x1 * sw[6] + y0 * sw[2] + y1 * sw[0];
            const float dF1 = x1 * sw[8] + x2 * sw[6] + y1 * sw[2] + y2 * sw[0];
            const float nF0 = a0 * sw[8] + a1 * sw[6] + b0 * sw[2] + b1 * sw[0];
            const float nF1 = a1 * sw[8] + a2 * sw[6] + b1 * sw[2] + b2 * sw[0];

            const float d0 = q ? dF0 : dC0, n0 = q ? nF0 : nC0;
            const float d1 = q ? dC1 : dF0, n1 = q ? nC1 : nF0;
            const float d2 = q ? dF1 : dC1, n2 = q ? nF1 : nC1;
            const float d3 = q ? dC2 : dF1, n3 = q ? nC2 : nF1;

            f4_t gv, qv;
            gv[0] = fmaf(0.5f * n0, __builtin_amdgcn_rcpf(d0 + EPS_), bv);
            gv[1] = fmaf(0.5f * n1, __builtin_amdgcn_rcpf(d1 + EPS_), bv);
            gv[2] = fmaf(0.5f * n2, __builtin_amdgcn_rcpf(d2 + EPS_), bv);
            gv[3] = fmaf(0.5f * n3, __builtin_amdgcn_rcpf(d3 + EPS_), bv);
            qv[0] = d0 * i0; qv[1] = d1 * i1; qv[2] = d2 * i0; qv[3] = d3 * i1;

            const int c0 = h + (k << 2);
            __builtin_nontemporal_store(gv, (f4_t*)(o0 + c0));
            __builtin_nontemporal_store(qv, (f4_t*)(o1 + c0));
        }
    }
#undef VAL
}

extern "C" void kernel_launch(void* const* d_in, const int* in_sizes, int n_in,
                              void* d_out, int out_size, void* d_ws, size_t ws_size,
                              hipStream_t stream) {
    const float* d    = (const float*)d_in[0];
    const float* cd   = (const float*)d_in[1];
    const float* gy   = (const float*)d_in[2];
    const float* cgy  = (const float*)d_in[3];
    const float* wpr  = (const float*)d_in[4];
    const float* swr  = (const float*)d_in[5];
    const float* bias = (const float*)d_in[6];
    float* out = (float*)d_out;

    dim3 grid(88, B_ * C_);    // 88 row-groups (4 output rows each) x 64 planes
    structn_rows<<<grid, NTH, 0, stream>>>(d, cd, gy, cgy, wpr, swr, bias, out);
}